// Round 9
// baseline (26.462 us; speedup 1.0000x reference)
//
#include <hip/hip_runtime.h>

// 3x3 cross-correlation, padding=1, NCHW, fp32 in/out, bf16 MFMA compute.
// out[b,o,h,w] = bias[o] + sum_{i,c} comb[o, i*16+c] * x[b,c,h+dy_i,w+dx_i]
// B=4, C=16, O=16, H=450, W=480. K = 144 = 9 flows x 16 c, padded to 5x32.
//
// Round 9: 2-deep stage split of R8 (global phase mixing). R8 = one big
// read burst -> barrier -> compute+store, convoyed chip-wide. Here:
//   stageA(rows 0..7) -> issue loadB(rows 8..13) to regs -> bar
//   -> compute rows 0..5 (+stores; loadB in flight) -> cvt+write rows 8..13
//   (disjoint LDS, race-free) -> bar -> compute rows 6..11.
// Same grid 760 = 8*95 (all resident, balanced), same 46.6KB LDS (3/CU),
// same float2 staging items, same MFMA core as R8.

#define HH 450
#define WW 480
#define BB 4
#define CC 16
#define OO 16
#define WT    96                 // output pixels per block (width), 6 tiles
#define WQN   5                  // width groups
#define WIN   104                // staged wi count (w0-4 .. w0+99)
#define RSTG  14                 // staged rows per block
#define ROUT  12                 // output rows per block
#define GR    6                  // output rows per compute group
#define HG    38                 // row-groups: ceil(450/12)
#define NTILE 6                  // 16-pixel MFMA tiles per row
#define W2N   52                 // float2 groups per staged row
#define HALF_A  (8 * W2N)        // 416 items per c-half (rows 0..7)
#define ITEMS_A (2 * HALF_A)     // 832
#define HALF_B  (6 * W2N)        // 312 items per c-half (rows 8..13)
#define ITEMS_B (2 * HALF_B)     // 624
#define PLANE   (RSTG * WIN)     // LDS rows per c-half
#define NBLK  (BB * WQN * HG)    // 760 = 8 * 95

typedef __attribute__((ext_vector_type(8))) short    bf16x8;
typedef __attribute__((ext_vector_type(4))) float    f32x4;
typedef __attribute__((ext_vector_type(4))) unsigned u32x4;

static __device__ __forceinline__ unsigned cvt_pk_bf16(float a, float b) {
    unsigned r;
    asm("v_cvt_pk_bf16_f32 %0, %1, %2" : "=v"(r) : "v"(a), "v"(b));
    return r;   // lo16 = bf16(a), hi16 = bf16(b), RNE
}

__global__ __launch_bounds__(256, 3) void flow_mfma_kernel(
    const float* __restrict__ x, const float* __restrict__ comb,
    const float* __restrict__ bias, float* __restrict__ out)
{
    // flat [2 c-half planes x 14 rows x 104 wi][8 shorts] : 46592 B
    __shared__ __align__(16) short xs[2 * PLANE][8];

    const int tid  = threadIdx.x;
    const int lane = tid & 63;
    const int wv   = tid >> 6;

    // ---- bijective XCD swizzle: 760 = 8*95 exactly ----
    int bid = blockIdx.x;
    int L   = (bid & 7) * 95 + (bid >> 3);
    int hg  = L % HG;
    int t2  = L / HG;
    int wq  = t2 % WQN;
    int b   = t2 / WQN;
    int h0  = hg * ROUT;
    int w0  = wq * WT;

    // ---- A-frags: weights fp32->bf16 once, in VGPRs ----
    const int col = lane & 15;          // pixel-in-tile (B col) / output o (A row)
    const int grp = lane >> 4;          // 0..3
    bf16x8 af[5];
    #pragma unroll
    for (int m = 0; m < 5; ++m) {
        int k0 = m * 32 + grp * 8;
        u32x4 p;
        if (k0 < 144) {
            float4 u = *(const float4*)(comb + col * 144 + k0);
            float4 v = *(const float4*)(comb + col * 144 + k0 + 4);
            p[0] = cvt_pk_bf16(u.x, u.y);
            p[1] = cvt_pk_bf16(u.z, u.w);
            p[2] = cvt_pk_bf16(v.x, v.y);
            p[3] = cvt_pk_bf16(v.z, v.w);
        } else {
            p[0] = p[1] = p[2] = p[3] = 0u;
        }
        af[m] = __builtin_bit_cast(bf16x8, p);
    }
    f32x4 bv = *(const f32x4*)(bias + grp * 4);

    // ---- per-lane B-frag column offsets (row-independent part) ----
    const int fo = grp >> 1;
    const int ch = grp & 1;
    int cof[5];
    #pragma unroll
    for (int m = 0; m < 4; ++m) {
        int i  = 2 * m + fo;
        int ky = i / 3;
        int kx = i - ky * 3;
        cof[m] = ch * PLANE + ky * WIN + col + kx + 3;
    }
    cof[4] = ch * PLANE + 2 * WIN + col + 5;   // flow 8 (ky=2, kx=2)

    // ---- stage A: rows 0..7 (load + cvt + LDS write) ----
    auto stageA = [&](int s) {
        int cs  = (s >= HALF_A) ? 1 : 0;
        int rem = s - cs * HALF_A;
        int r   = rem / W2N;              // 0..7
        int wi2 = rem - r * W2N;
        int hy  = h0 - 1 + r;
        int w   = w0 - 4 + wi2 * 2;
        u32x4 p0, p1;
        if (((unsigned)hy < (unsigned)HH) && ((unsigned)w < (unsigned)WW)) {
            const float* xp = x + (((size_t)(b * CC + cs * 8) * HH + hy) * WW + w);
            float fx[8], fy[8];
            #pragma unroll
            for (int j = 0; j < 8; ++j) {
                float2 v = *(const float2*)(xp + (size_t)j * HH * WW);
                fx[j] = v.x; fy[j] = v.y;
            }
            p0[0] = cvt_pk_bf16(fx[0], fx[1]); p0[1] = cvt_pk_bf16(fx[2], fx[3]);
            p0[2] = cvt_pk_bf16(fx[4], fx[5]); p0[3] = cvt_pk_bf16(fx[6], fx[7]);
            p1[0] = cvt_pk_bf16(fy[0], fy[1]); p1[1] = cvt_pk_bf16(fy[2], fy[3]);
            p1[2] = cvt_pk_bf16(fy[4], fy[5]); p1[3] = cvt_pk_bf16(fy[6], fy[7]);
        } else {
            p0[0] = p0[1] = p0[2] = p0[3] = 0u;
            p1[0] = p1[1] = p1[2] = p1[3] = 0u;
        }
        int r2 = cs * PLANE + r * WIN + wi2 * 2;
        *(u32x4*)(&xs[r2][0])     = p0;
        *(u32x4*)(&xs[r2 + 1][0]) = p1;
    };
    #pragma unroll
    for (int it = 0; it < 3; ++it)        // 768 items
        stageA(tid + it * 256);
    if (tid < ITEMS_A - 3 * 256)          // tail: 64
        stageA(tid + 3 * 256);

    // ---- issue loads for rows 8..13 into registers (in flight past bar) ----
    float fa[3][8], fb[3][8];
    int   wofs[3];
    #pragma unroll
    for (int it = 0; it < 3; ++it) {
        int s   = tid + it * 256;
        bool act = (s < ITEMS_B);
        int cs  = (s >= HALF_B) ? 1 : 0;
        int rem = s - cs * HALF_B;
        int r   = rem / W2N;              // 0..5 -> staged row 8+r
        int wi2 = rem - r * W2N;
        int hy  = h0 + 7 + r;             // >= 7, only upper bound matters
        int w   = w0 - 4 + wi2 * 2;
        wofs[it] = act ? (cs * PLANE + (8 + r) * WIN + wi2 * 2) : -1;
        if (act && (hy < HH) && ((unsigned)w < (unsigned)WW)) {
            const float* xp = x + (((size_t)(b * CC + cs * 8) * HH + hy) * WW + w);
            #pragma unroll
            for (int j = 0; j < 8; ++j) {
                float2 v = *(const float2*)(xp + (size_t)j * HH * WW);
                fa[it][j] = v.x; fb[it][j] = v.y;
            }
        } else {
            #pragma unroll
            for (int j = 0; j < 8; ++j) { fa[it][j] = 0.0f; fb[it][j] = 0.0f; }
        }
    }
    __syncthreads();                      // rows 0..7 ready

    // ---- compute group g: output rows g*6 .. g*6+5, 36 tiles round-robin ----
    auto compute = [&](int g) {
        #pragma unroll
        for (int k = 0; k < 9; ++k) {
            int idx = wv + 4 * k;         // 0..35
            int row = idx / 6;
            int t   = idx - row * 6;
            int rs  = g * GR + row;
            int h   = h0 + rs;
            if (h >= HH) continue;
            int n0 = t * 16;
            int rbase = rs * WIN + n0;
            f32x4 acc = bv;
            #pragma unroll
            for (int m = 0; m < 4; ++m) {
                bf16x8 bf = *(const bf16x8*)(&xs[rbase + cof[m]][0]);
                acc = __builtin_amdgcn_mfma_f32_16x16x32_bf16(af[m], bf, acc, 0, 0, 0);
            }
            bf16x8 b4;
            if (grp < 2) {
                b4 = *(const bf16x8*)(&xs[rbase + cof[4]][0]);
            } else {
                #pragma unroll
                for (int j = 0; j < 8; ++j) b4[j] = 0;
            }
            acc = __builtin_amdgcn_mfma_f32_16x16x32_bf16(af[4], b4, acc, 0, 0, 0);

            float* op = out + (((size_t)(b * OO + grp * 4) * HH + h) * WW + w0 + n0 + col);
            #pragma unroll
            for (int j = 0; j < 4; ++j)
                op[(size_t)j * HH * WW] = acc[j];
        }
    };

    compute(0);                           // reads staged rows 0..7 only

    // ---- write rows 8..13 (disjoint from compute(0) reads -> race-free) ----
    #pragma unroll
    for (int it = 0; it < 3; ++it) {
        if (wofs[it] >= 0) {
            u32x4 p0, p1;
            p0[0] = cvt_pk_bf16(fa[it][0], fa[it][1]);
            p0[1] = cvt_pk_bf16(fa[it][2], fa[it][3]);
            p0[2] = cvt_pk_bf16(fa[it][4], fa[it][5]);
            p0[3] = cvt_pk_bf16(fa[it][6], fa[it][7]);
            p1[0] = cvt_pk_bf16(fb[it][0], fb[it][1]);
            p1[1] = cvt_pk_bf16(fb[it][2], fb[it][3]);
            p1[2] = cvt_pk_bf16(fb[it][4], fb[it][5]);
            p1[3] = cvt_pk_bf16(fb[it][6], fb[it][7]);
            *(u32x4*)(&xs[wofs[it]][0])     = p0;
            *(u32x4*)(&xs[wofs[it] + 1][0]) = p1;
        }
    }
    __syncthreads();                      // rows 8..13 ready

    compute(1);                           // reads staged rows 6..13
}

extern "C" void kernel_launch(void* const* d_in, const int* in_sizes, int n_in,
                              void* d_out, int out_size, void* d_ws, size_t ws_size,
                              hipStream_t stream) {
    const float* x    = (const float*)d_in[0];
    const float* comb = (const float*)d_in[1];
    const float* bias = (const float*)d_in[2];
    float* out        = (float*)d_out;

    flow_mfma_kernel<<<NBLK, 256, 0, stream>>>(x, comb, bias, out);
}